// Round 6
// baseline (447.226 us; speedup 1.0000x reference)
//
#include <hip/hip_runtime.h>
#include <hip/hip_bf16.h>

// ToxDL GCN, round 5: split pooling (parallel partial sums) from head.
// act(bf16) @ Wt(bf16,[N][K]) -> h(bf16) -> CSR gather (fp32 accum) -> next act(bf16)
// Layer 4 gather emits fp32; pool_partial does chunked segment-sum (batch sorted,
// atomicAdd only at graph boundaries); head does mean, L2-norm, concat, MLP.

#define N_NODES 10000
#define N_EDGES 160000
#define NGRAPH  64
#define MPAD    10112   // 79*128
#define PCHUNK  16

typedef __attribute__((ext_vector_type(8))) short short8;
typedef __attribute__((ext_vector_type(4))) float f32x4;
typedef __attribute__((ext_vector_type(4))) unsigned short u16x4;

__device__ __forceinline__ unsigned short f2bf(float f) {
    unsigned u = __float_as_uint(f);
    return (unsigned short)((u + 0x7FFFu + ((u >> 16) & 1u)) >> 16);
}
__device__ __forceinline__ float bf2f(unsigned short u) {
    return __uint_as_float(((unsigned)u) << 16);
}
__device__ __forceinline__ void gl_lds16(const void* g, void* l) {
    __builtin_amdgcn_global_load_lds(
        (const __attribute__((address_space(1))) unsigned*)g,
        (__attribute__((address_space(3))) unsigned*)l, 16, 0, 0);
}

// ---------------- utility ----------------
__global__ __launch_bounds__(256) void zero_i32(int* p, int n) {
    int i = blockIdx.x * 256 + threadIdx.x;
    if (i < n) p[i] = 0;
}
__global__ __launch_bounds__(256) void zero_f32(float* p, int n) {
    int i = blockIdx.x * 256 + threadIdx.x;
    if (i < n) p[i] = 0.0f;
}

// ---------------- convert fp32 -> bf16 (flat, 4/thread) ----------------
__global__ __launch_bounds__(256) void conv_bf16(const float4* __restrict__ in,
                                                 u16x4* __restrict__ out, int n4) {
    int i = blockIdx.x * 256 + threadIdx.x;
    if (i >= n4) return;
    float4 v = in[i];
    u16x4 o;
    o.x = f2bf(v.x); o.y = f2bf(v.y); o.z = f2bf(v.z); o.w = f2bf(v.w);
    out[i] = o;
}

// ---------------- W[K][N] fp32 -> Wt[N][K] bf16 ----------------
__global__ __launch_bounds__(256) void conv_transpose_w(const float* __restrict__ W,
                                                        unsigned short* __restrict__ Wt,
                                                        int K, int N) {
    __shared__ float t[32][33];
    int k0 = blockIdx.x * 32, n0 = blockIdx.y * 32;
    int tx = threadIdx.x & 31, ty = threadIdx.x >> 5;  // ty 0..7
#pragma unroll
    for (int i = 0; i < 4; i++)
        t[ty + i * 8][tx] = W[(size_t)(k0 + ty + i * 8) * N + n0 + tx];
    __syncthreads();
#pragma unroll
    for (int i = 0; i < 4; i++)
        Wt[(size_t)(n0 + ty + i * 8) * K + k0 + tx] = f2bf(t[tx][ty + i * 8]);
}

// ---------------- CSR build ----------------
__global__ __launch_bounds__(256) void deg_count(const int* __restrict__ dst, int* __restrict__ degc, int E) {
    int e = blockIdx.x * 256 + threadIdx.x;
    if (e < E) atomicAdd(&degc[dst[e]], 1);
}
__global__ __launch_bounds__(256) void deg_fin(const int* __restrict__ degc, float* __restrict__ dis, int n) {
    int i = blockIdx.x * 256 + threadIdx.x;
    if (i < n) dis[i] = 1.0f / sqrtf((float)(degc[i] + 1));
}
__global__ __launch_bounds__(1024) void scan_offsets(const int* __restrict__ cnt,
                                                     int* __restrict__ off, int n) {
    __shared__ int buf[1024];
    __shared__ int carry;
    int t = threadIdx.x;
    if (t == 0) { carry = 0; off[0] = 0; }
    __syncthreads();
    for (int base = 0; base < n; base += 1024) {
        int v = (base + t < n) ? cnt[base + t] : 0;
        buf[t] = v;
        __syncthreads();
#pragma unroll
        for (int o = 1; o < 1024; o <<= 1) {
            int add = (t >= o) ? buf[t - o] : 0;
            __syncthreads();
            buf[t] += add;
            __syncthreads();
        }
        if (base + t < n) off[base + t + 1] = buf[t] + carry;
        __syncthreads();
        if (t == 0) carry += buf[1023];
        __syncthreads();
    }
}
__global__ __launch_bounds__(256) void csr_fill(const int* __restrict__ srcI,
                                                const int* __restrict__ dstI,
                                                const int* __restrict__ off,
                                                int* __restrict__ fc,
                                                const float* __restrict__ dis,
                                                int* __restrict__ csr_src,
                                                float* __restrict__ csr_w, int E) {
    int e = blockIdx.x * 256 + threadIdx.x;
    if (e >= E) return;
    int d = dstI[e];
    int s = srcI[e];
    int pos = off[d] + atomicAdd(&fc[d], 1);
    csr_src[pos] = s;
    csr_w[pos] = dis[s];
}

// ---------------- bf16 MFMA GEMM: C[MPAD][N](bf16) = A[<=10000][K](bf16) @ Bt[N][K]^T ----------------
// 128x128 tile, BK=64, 256 threads (4 waves, 2x2 of 64x64), mfma 16x16x32.
__global__ __launch_bounds__(256) void gemm_bf16(const unsigned short* __restrict__ A,
                                                 const unsigned short* __restrict__ Bt,
                                                 unsigned short* __restrict__ C,
                                                 int K, int N) {
    __shared__ short lA[128 * 64];
    __shared__ short lB[128 * 64];
    int tid = threadIdx.x;
    int lane = tid & 63;
    int wave = tid >> 6;
    int rm = blockIdx.y, cn = blockIdx.x;
    int wr = wave >> 1, wc = wave & 1;

    f32x4 acc[4][4];
#pragma unroll
    for (int m = 0; m < 4; m++)
#pragma unroll
        for (int n = 0; n < 4; n++) acc[m][n] = (f32x4){0.f, 0.f, 0.f, 0.f};

    int lr = lane >> 3;          // row within 8-row segment
    int lc = (lane & 7) * 8;     // elem offset within BK=64

    for (int k0 = 0; k0 < K; k0 += 64) {
        __syncthreads();
#pragma unroll
        for (int i = 0; i < 4; i++) {
            int s = wave * 4 + i;
            int row = rm * 128 + s * 8 + lr;
            if (row > N_NODES - 1) row = N_NODES - 1;   // clamp tail (dup rows, never read downstream)
            gl_lds16(A + (size_t)row * K + k0 + lc, &lA[s * 512]);
        }
#pragma unroll
        for (int i = 0; i < 4; i++) {
            int s = wave * 4 + i;
            int row = cn * 128 + s * 8 + lr;            // always < N
            gl_lds16(Bt + (size_t)row * K + k0 + lc, &lB[s * 512]);
        }
        __syncthreads();
#pragma unroll
        for (int kk = 0; kk < 64; kk += 32) {
            short8 a[4], b[4];
#pragma unroll
            for (int m = 0; m < 4; m++)
                a[m] = *(const short8*)&lA[(wr * 64 + m * 16 + (lane & 15)) * 64 + kk + (lane >> 4) * 8];
#pragma unroll
            for (int n = 0; n < 4; n++)
                b[n] = *(const short8*)&lB[(wc * 64 + n * 16 + (lane & 15)) * 64 + kk + (lane >> 4) * 8];
#pragma unroll
            for (int m = 0; m < 4; m++)
#pragma unroll
                for (int n = 0; n < 4; n++)
                    acc[m][n] = __builtin_amdgcn_mfma_f32_16x16x32_bf16(a[m], b[n], acc[m][n], 0, 0, 0);
        }
    }
    int r0 = rm * 128 + wr * 64 + (lane >> 4) * 4;
    int c0 = cn * 128 + wc * 64 + (lane & 15);
#pragma unroll
    for (int m = 0; m < 4; m++)
#pragma unroll
        for (int n = 0; n < 4; n++)
#pragma unroll
            for (int j = 0; j < 4; j++)
                C[(size_t)(r0 + m * 16 + j) * N + c0 + n * 16] = f2bf(acc[m][n][j]);
}

// ---------------- per-node CSR gather, fused self-loop + bias (+relu) ----------------
template<int D, bool RELU, bool OUTBF>
__global__ __launch_bounds__(D / 4) void gather_nodes(const unsigned short* __restrict__ h,
                                                      const int* __restrict__ off,
                                                      const int* __restrict__ csr_src,
                                                      const float* __restrict__ csr_w,
                                                      const float* __restrict__ dis,
                                                      const float4* __restrict__ bias,
                                                      void* __restrict__ outp) {
    int n = blockIdx.x;
    int f = threadIdx.x;
    float dn = dis[n];
    u16x4 hv = ((const u16x4*)(h + (size_t)n * D))[f];
    float ax = dn * bf2f(hv.x), ay = dn * bf2f(hv.y), az = dn * bf2f(hv.z), aw = dn * bf2f(hv.w);
    int kb = off[n], ke = off[n + 1];
    for (int k = kb; k < ke; k++) {
        int s = csr_src[k];
        float w = csr_w[k];
        u16x4 v = ((const u16x4*)(h + (size_t)s * D))[f];
        ax += w * bf2f(v.x); ay += w * bf2f(v.y); az += w * bf2f(v.z); aw += w * bf2f(v.w);
    }
    float4 bb = bias[f];
    float ox = ax * dn + bb.x, oy = ay * dn + bb.y, oz = az * dn + bb.z, ow = aw * dn + bb.w;
    if (RELU) {
        ox = fmaxf(ox, 0.f); oy = fmaxf(oy, 0.f); oz = fmaxf(oz, 0.f); ow = fmaxf(ow, 0.f);
    }
    if (OUTBF) {
        u16x4 o; o.x = f2bf(ox); o.y = f2bf(oy); o.z = f2bf(oz); o.w = f2bf(ow);
        ((u16x4*)outp)[(size_t)n * (D / 4) + f] = o;
    } else {
        ((float4*)outp)[(size_t)n * (D / 4) + f] = make_float4(ox, oy, oz, ow);
    }
}

// ---------------- parallel pooling: chunked segment-sum (batch sorted) ----------------
__global__ __launch_bounds__(256) void pool_partial(const float* __restrict__ agg,
                                                    const int* __restrict__ batch,
                                                    float* __restrict__ pool) {
    int c0 = blockIdx.x * PCHUNK;
    int t = threadIdx.x;
    int end = c0 + PCHUNK;
    if (end > N_NODES) end = N_NODES;
    float acc = 0.0f;
    int cur = batch[c0];
    for (int n = c0; n < end; n++) {
        int g = batch[n];
        if (g != cur) {
            atomicAdd(&pool[cur * 256 + t], acc);
            acc = 0.0f;
            cur = g;
        }
        acc += agg[(size_t)n * 256 + t];
    }
    atomicAdd(&pool[cur * 256 + t], acc);
}

// ---------------- head: mean, L2-normalize, concat, 3-layer MLP ----------------
__device__ __forceinline__ int lbound(const int* __restrict__ a, int n, int key) {
    int lo = 0, hi = n;
    while (lo < hi) {
        int mid = (lo + hi) >> 1;
        if (a[mid] < key) lo = mid + 1; else hi = mid;
    }
    return lo;
}

__global__ __launch_bounds__(256) void head(const float* __restrict__ pool,
                                            const int* __restrict__ batch,
                                            const float* __restrict__ vec,
                                            const float* __restrict__ cW1, const float* __restrict__ cb1,
                                            const float* __restrict__ cW2, const float* __restrict__ cb2,
                                            const float* __restrict__ cW3, const float* __restrict__ cb3,
                                            float* __restrict__ out) {
    int g = blockIdx.x;
    int t = threadIdx.x;  // 256 threads = D_OUT
    __shared__ float comb[512];
    __shared__ float z1s[256];
    __shared__ float z2s[64];
    __shared__ float red[4];

    int lo = lbound(batch, N_NODES, g);
    int hi = lbound(batch, N_NODES, g + 1);
    float c = fmaxf((float)(hi - lo), 1.0f);
    float pm = pool[g * 256 + t] / c;

    float ss = pm * pm;
#pragma unroll
    for (int o = 32; o; o >>= 1) ss += __shfl_down(ss, o);
    if ((t & 63) == 0) red[t >> 6] = ss;
    __syncthreads();
    if (t == 0) {
        float tot = red[0] + red[1] + red[2] + red[3];
        red[0] = 1.0f / fmaxf(sqrtf(tot), 1e-12f);
    }
    __syncthreads();
    float scale = red[0];
    comb[t] = pm * scale;
    comb[256 + t] = vec[g * 256 + t];
    __syncthreads();

    float s1 = cb1[t];
#pragma unroll 4
    for (int i = 0; i < 512; i++) s1 += comb[i] * cW1[i * 256 + t];
    z1s[t] = fmaxf(s1, 0.0f);
    __syncthreads();

    if (t < 64) {
        float s2 = cb2[t];
#pragma unroll 4
        for (int i = 0; i < 256; i++) s2 += z1s[i] * cW2[i * 64 + t];
        z2s[t] = fmaxf(s2, 0.0f);
    }
    __syncthreads();

    if (t == 0) {
        float s3 = cb3[0];
        for (int i = 0; i < 64; i++) s3 += z2s[i] * cW3[i];
        out[g] = 1.0f / (1.0f + expf(-s3));
    }
}

extern "C" void kernel_launch(void* const* d_in, const int* in_sizes, int n_in,
                              void* d_out, int out_size, void* d_ws, size_t ws_size,
                              hipStream_t stream) {
    const float* x   = (const float*)d_in[0];
    const int*   ei  = (const int*)d_in[1];
    const int*   bat = (const int*)d_in[2];
    const float* vec = (const float*)d_in[3];
    const float* W1 = (const float*)d_in[4];
    const float* b1 = (const float*)d_in[5];
    const float* W2 = (const float*)d_in[6];
    const float* b2 = (const float*)d_in[7];
    const float* W3 = (const float*)d_in[8];
    const float* b3 = (const float*)d_in[9];
    const float* W4 = (const float*)d_in[10];
    const float* b4 = (const float*)d_in[11];
    const float* cW1 = (const float*)d_in[12];
    const float* cb1 = (const float*)d_in[13];
    const float* cW2 = (const float*)d_in[14];
    const float* cb2 = (const float*)d_in[15];
    const float* cW3 = (const float*)d_in[16];
    const float* cb3 = (const float*)d_in[17];

    const int* srcI = ei;
    const int* dstI = ei + N_EDGES;

    char* base = (char*)d_ws;
    float* dis      = (float*)base;            base += N_NODES * 4;
    int*   degc     = (int*)base;              base += N_NODES * 4;
    int*   off      = (int*)base;              base += (N_NODES + 1) * 4;
    int*   fc       = (int*)base;              base += N_NODES * 4 + 4;
    int*   csr_src  = (int*)base;              base += N_EDGES * 4;
    float* csr_w    = (float*)base;            base += N_EDGES * 4;
    float* pool     = (float*)base;            base += NGRAPH * 256 * 4;
    unsigned short* xb   = (unsigned short*)base;  base += (size_t)N_NODES * 1280 * 2;  // aliased by agg4 later
    unsigned short* W1t  = (unsigned short*)base;  base += 512 * 1280 * 2;
    unsigned short* W2t  = (unsigned short*)base;  base += 512 * 512 * 2;
    unsigned short* W3t  = (unsigned short*)base;  base += 512 * 512 * 2;
    unsigned short* W4t  = (unsigned short*)base;  base += 256 * 512 * 2;
    unsigned short* h    = (unsigned short*)base;  base += (size_t)MPAD * 512 * 2;
    unsigned short* aggb = (unsigned short*)base;  base += (size_t)N_NODES * 512 * 2;
    float* agg4 = (float*)xb;  // alias: xb dead after GEMM1, agg4 written by gather4

    // ---- conversions ----
    conv_bf16<<<(N_NODES * 1280 / 4 + 255) / 256, 256, 0, stream>>>((const float4*)x, (u16x4*)xb, N_NODES * 1280 / 4);
    conv_transpose_w<<<dim3(1280 / 32, 512 / 32), 256, 0, stream>>>(W1, W1t, 1280, 512);
    conv_transpose_w<<<dim3(512 / 32, 512 / 32), 256, 0, stream>>>(W2, W2t, 512, 512);
    conv_transpose_w<<<dim3(512 / 32, 512 / 32), 256, 0, stream>>>(W3, W3t, 512, 512);
    conv_transpose_w<<<dim3(512 / 32, 256 / 32), 256, 0, stream>>>(W4, W4t, 512, 256);

    // ---- CSR build ----
    zero_i32<<<(N_NODES + 255) / 256, 256, 0, stream>>>(degc, N_NODES);
    zero_i32<<<(N_NODES + 255) / 256, 256, 0, stream>>>(fc, N_NODES);
    deg_count<<<(N_EDGES + 255) / 256, 256, 0, stream>>>(dstI, degc, N_EDGES);
    deg_fin<<<(N_NODES + 255) / 256, 256, 0, stream>>>(degc, dis, N_NODES);
    scan_offsets<<<1, 1024, 0, stream>>>(degc, off, N_NODES);
    csr_fill<<<(N_EDGES + 255) / 256, 256, 0, stream>>>(srcI, dstI, off, fc, dis, csr_src, csr_w, N_EDGES);

    // ---- layer 1 ----
    gemm_bf16<<<dim3(512 / 128, MPAD / 128), 256, 0, stream>>>(xb, W1t, h, 1280, 512);
    gather_nodes<512, true, true><<<N_NODES, 128, 0, stream>>>(h, off, csr_src, csr_w, dis,
                                                               (const float4*)b1, aggb);
    // ---- layer 2 ----
    gemm_bf16<<<dim3(512 / 128, MPAD / 128), 256, 0, stream>>>(aggb, W2t, h, 512, 512);
    gather_nodes<512, true, true><<<N_NODES, 128, 0, stream>>>(h, off, csr_src, csr_w, dis,
                                                               (const float4*)b2, aggb);
    // ---- layer 3 ----
    gemm_bf16<<<dim3(512 / 128, MPAD / 128), 256, 0, stream>>>(aggb, W3t, h, 512, 512);
    gather_nodes<512, true, true><<<N_NODES, 128, 0, stream>>>(h, off, csr_src, csr_w, dis,
                                                               (const float4*)b3, aggb);
    // ---- layer 4 (no relu, fp32 out) ----
    gemm_bf16<<<dim3(256 / 128, MPAD / 128), 256, 0, stream>>>(aggb, W4t, h, 512, 256);
    gather_nodes<256, false, false><<<N_NODES, 64, 0, stream>>>(h, off, csr_src, csr_w, dis,
                                                                (const float4*)b4, agg4);

    // ---- pooling + head ----
    zero_f32<<<(NGRAPH * 256 + 255) / 256, 256, 0, stream>>>(pool, NGRAPH * 256);
    pool_partial<<<(N_NODES + PCHUNK - 1) / PCHUNK, 256, 0, stream>>>(agg4, bat, pool);
    head<<<NGRAPH, 256, 0, stream>>>(pool, bat, vec, cW1, cb1, cW2, cb2, cW3, cb3, (float*)d_out);
}

// Round 7
// 413.485 us; speedup vs baseline: 1.0816x; 1.0816x over previous
//
#include <hip/hip_runtime.h>
#include <hip/hip_bf16.h>

// ToxDL GCN, round 6: wave-parallel head (kill the latency-bound 64-block MLP).
// act(bf16) @ Wt(bf16,[N][K]) -> h(bf16) -> CSR gather (fp32 accum) -> next act(bf16)
// Pool: chunked segment-sum. Head: comb build -> wave-per-output z1 -> z2z3.

#define N_NODES 10000
#define N_EDGES 160000
#define NGRAPH  64
#define MPAD    10112   // 79*128
#define PCHUNK  16

typedef __attribute__((ext_vector_type(8))) short short8;
typedef __attribute__((ext_vector_type(4))) float f32x4;
typedef __attribute__((ext_vector_type(4))) unsigned short u16x4;

__device__ __forceinline__ unsigned short f2bf(float f) {
    unsigned u = __float_as_uint(f);
    return (unsigned short)((u + 0x7FFFu + ((u >> 16) & 1u)) >> 16);
}
__device__ __forceinline__ float bf2f(unsigned short u) {
    return __uint_as_float(((unsigned)u) << 16);
}
__device__ __forceinline__ void gl_lds16(const void* g, void* l) {
    __builtin_amdgcn_global_load_lds(
        (const __attribute__((address_space(1))) unsigned*)g,
        (__attribute__((address_space(3))) unsigned*)l, 16, 0, 0);
}

// ---------------- utility ----------------
__global__ __launch_bounds__(256) void zero_i32(int* p, int n) {
    int i = blockIdx.x * 256 + threadIdx.x;
    if (i < n) p[i] = 0;
}
__global__ __launch_bounds__(256) void zero_f32(float* p, int n) {
    int i = blockIdx.x * 256 + threadIdx.x;
    if (i < n) p[i] = 0.0f;
}

// ---------------- convert fp32 -> bf16 (flat, 4/thread) ----------------
__global__ __launch_bounds__(256) void conv_bf16(const float4* __restrict__ in,
                                                 u16x4* __restrict__ out, int n4) {
    int i = blockIdx.x * 256 + threadIdx.x;
    if (i >= n4) return;
    float4 v = in[i];
    u16x4 o;
    o.x = f2bf(v.x); o.y = f2bf(v.y); o.z = f2bf(v.z); o.w = f2bf(v.w);
    out[i] = o;
}

// ---------------- W[K][N] fp32 -> Wt[N][K] bf16 ----------------
__global__ __launch_bounds__(256) void conv_transpose_w(const float* __restrict__ W,
                                                        unsigned short* __restrict__ Wt,
                                                        int K, int N) {
    __shared__ float t[32][33];
    int k0 = blockIdx.x * 32, n0 = blockIdx.y * 32;
    int tx = threadIdx.x & 31, ty = threadIdx.x >> 5;  // ty 0..7
#pragma unroll
    for (int i = 0; i < 4; i++)
        t[ty + i * 8][tx] = W[(size_t)(k0 + ty + i * 8) * N + n0 + tx];
    __syncthreads();
#pragma unroll
    for (int i = 0; i < 4; i++)
        Wt[(size_t)(n0 + ty + i * 8) * K + k0 + tx] = f2bf(t[tx][ty + i * 8]);
}

// ---------------- W[K][N] fp32 -> Wt[N][K] fp32 (for head weights) ----------------
__global__ __launch_bounds__(256) void transpose_f32(const float* __restrict__ W,
                                                     float* __restrict__ Wt,
                                                     int K, int N) {
    __shared__ float t[32][33];
    int k0 = blockIdx.x * 32, n0 = blockIdx.y * 32;
    int tx = threadIdx.x & 31, ty = threadIdx.x >> 5;
#pragma unroll
    for (int i = 0; i < 4; i++)
        t[ty + i * 8][tx] = W[(size_t)(k0 + ty + i * 8) * N + n0 + tx];
    __syncthreads();
#pragma unroll
    for (int i = 0; i < 4; i++)
        Wt[(size_t)(n0 + ty + i * 8) * K + k0 + tx] = t[tx][ty + i * 8];
}

// ---------------- CSR build ----------------
__global__ __launch_bounds__(256) void deg_count(const int* __restrict__ dst, int* __restrict__ degc, int E) {
    int e = blockIdx.x * 256 + threadIdx.x;
    if (e < E) atomicAdd(&degc[dst[e]], 1);
}
__global__ __launch_bounds__(256) void deg_fin(const int* __restrict__ degc, float* __restrict__ dis, int n) {
    int i = blockIdx.x * 256 + threadIdx.x;
    if (i < n) dis[i] = 1.0f / sqrtf((float)(degc[i] + 1));
}
__global__ __launch_bounds__(1024) void scan_offsets(const int* __restrict__ cnt,
                                                     int* __restrict__ off, int n) {
    __shared__ int buf[1024];
    __shared__ int carry;
    int t = threadIdx.x;
    if (t == 0) { carry = 0; off[0] = 0; }
    __syncthreads();
    for (int base = 0; base < n; base += 1024) {
        int v = (base + t < n) ? cnt[base + t] : 0;
        buf[t] = v;
        __syncthreads();
#pragma unroll
        for (int o = 1; o < 1024; o <<= 1) {
            int add = (t >= o) ? buf[t - o] : 0;
            __syncthreads();
            buf[t] += add;
            __syncthreads();
        }
        if (base + t < n) off[base + t + 1] = buf[t] + carry;
        __syncthreads();
        if (t == 0) carry += buf[1023];
        __syncthreads();
    }
}
__global__ __launch_bounds__(256) void csr_fill(const int* __restrict__ srcI,
                                                const int* __restrict__ dstI,
                                                const int* __restrict__ off,
                                                int* __restrict__ fc,
                                                const float* __restrict__ dis,
                                                int* __restrict__ csr_src,
                                                float* __restrict__ csr_w, int E) {
    int e = blockIdx.x * 256 + threadIdx.x;
    if (e >= E) return;
    int d = dstI[e];
    int s = srcI[e];
    int pos = off[d] + atomicAdd(&fc[d], 1);
    csr_src[pos] = s;
    csr_w[pos] = dis[s];
}

// ---------------- bf16 MFMA GEMM: C[MPAD][N](bf16) = A[<=10000][K](bf16) @ Bt[N][K]^T ----------------
__global__ __launch_bounds__(256) void gemm_bf16(const unsigned short* __restrict__ A,
                                                 const unsigned short* __restrict__ Bt,
                                                 unsigned short* __restrict__ C,
                                                 int K, int N) {
    __shared__ short lA[128 * 64];
    __shared__ short lB[128 * 64];
    int tid = threadIdx.x;
    int lane = tid & 63;
    int wave = tid >> 6;
    int rm = blockIdx.y, cn = blockIdx.x;
    int wr = wave >> 1, wc = wave & 1;

    f32x4 acc[4][4];
#pragma unroll
    for (int m = 0; m < 4; m++)
#pragma unroll
        for (int n = 0; n < 4; n++) acc[m][n] = (f32x4){0.f, 0.f, 0.f, 0.f};

    int lr = lane >> 3;
    int lc = (lane & 7) * 8;

    for (int k0 = 0; k0 < K; k0 += 64) {
        __syncthreads();
#pragma unroll
        for (int i = 0; i < 4; i++) {
            int s = wave * 4 + i;
            int row = rm * 128 + s * 8 + lr;
            if (row > N_NODES - 1) row = N_NODES - 1;
            gl_lds16(A + (size_t)row * K + k0 + lc, &lA[s * 512]);
        }
#pragma unroll
        for (int i = 0; i < 4; i++) {
            int s = wave * 4 + i;
            int row = cn * 128 + s * 8 + lr;
            gl_lds16(Bt + (size_t)row * K + k0 + lc, &lB[s * 512]);
        }
        __syncthreads();
#pragma unroll
        for (int kk = 0; kk < 64; kk += 32) {
            short8 a[4], b[4];
#pragma unroll
            for (int m = 0; m < 4; m++)
                a[m] = *(const short8*)&lA[(wr * 64 + m * 16 + (lane & 15)) * 64 + kk + (lane >> 4) * 8];
#pragma unroll
            for (int n = 0; n < 4; n++)
                b[n] = *(const short8*)&lB[(wc * 64 + n * 16 + (lane & 15)) * 64 + kk + (lane >> 4) * 8];
#pragma unroll
            for (int m = 0; m < 4; m++)
#pragma unroll
                for (int n = 0; n < 4; n++)
                    acc[m][n] = __builtin_amdgcn_mfma_f32_16x16x32_bf16(a[m], b[n], acc[m][n], 0, 0, 0);
        }
    }
    int r0 = rm * 128 + wr * 64 + (lane >> 4) * 4;
    int c0 = cn * 128 + wc * 64 + (lane & 15);
#pragma unroll
    for (int m = 0; m < 4; m++)
#pragma unroll
        for (int n = 0; n < 4; n++)
#pragma unroll
            for (int j = 0; j < 4; j++)
                C[(size_t)(r0 + m * 16 + j) * N + c0 + n * 16] = f2bf(acc[m][n][j]);
}

// ---------------- per-node CSR gather, fused self-loop + bias (+relu) ----------------
template<int D, bool RELU, bool OUTBF>
__global__ __launch_bounds__(D / 4) void gather_nodes(const unsigned short* __restrict__ h,
                                                      const int* __restrict__ off,
                                                      const int* __restrict__ csr_src,
                                                      const float* __restrict__ csr_w,
                                                      const float* __restrict__ dis,
                                                      const float4* __restrict__ bias,
                                                      void* __restrict__ outp) {
    int n = blockIdx.x;
    int f = threadIdx.x;
    float dn = dis[n];
    u16x4 hv = ((const u16x4*)(h + (size_t)n * D))[f];
    float ax = dn * bf2f(hv.x), ay = dn * bf2f(hv.y), az = dn * bf2f(hv.z), aw = dn * bf2f(hv.w);
    int kb = off[n], ke = off[n + 1];
    for (int k = kb; k < ke; k++) {
        int s = csr_src[k];
        float w = csr_w[k];
        u16x4 v = ((const u16x4*)(h + (size_t)s * D))[f];
        ax += w * bf2f(v.x); ay += w * bf2f(v.y); az += w * bf2f(v.z); aw += w * bf2f(v.w);
    }
    float4 bb = bias[f];
    float ox = ax * dn + bb.x, oy = ay * dn + bb.y, oz = az * dn + bb.z, ow = aw * dn + bb.w;
    if (RELU) {
        ox = fmaxf(ox, 0.f); oy = fmaxf(oy, 0.f); oz = fmaxf(oz, 0.f); ow = fmaxf(ow, 0.f);
    }
    if (OUTBF) {
        u16x4 o; o.x = f2bf(ox); o.y = f2bf(oy); o.z = f2bf(oz); o.w = f2bf(ow);
        ((u16x4*)outp)[(size_t)n * (D / 4) + f] = o;
    } else {
        ((float4*)outp)[(size_t)n * (D / 4) + f] = make_float4(ox, oy, oz, ow);
    }
}

// ---------------- parallel pooling: chunked segment-sum (batch sorted) ----------------
__global__ __launch_bounds__(256) void pool_partial(const float* __restrict__ agg,
                                                    const int* __restrict__ batch,
                                                    float* __restrict__ pool) {
    int c0 = blockIdx.x * PCHUNK;
    int t = threadIdx.x;
    int end = c0 + PCHUNK;
    if (end > N_NODES) end = N_NODES;
    float acc = 0.0f;
    int cur = batch[c0];
    for (int n = c0; n < end; n++) {
        int g = batch[n];
        if (g != cur) {
            atomicAdd(&pool[cur * 256 + t], acc);
            acc = 0.0f;
            cur = g;
        }
        acc += agg[(size_t)n * 256 + t];
    }
    atomicAdd(&pool[cur * 256 + t], acc);
}

// ---------------- head stage 1: mean + L2-normalize + concat -> comb[64][512] ----------------
__device__ __forceinline__ int lbound(const int* __restrict__ a, int n, int key) {
    int lo = 0, hi = n;
    while (lo < hi) {
        int mid = (lo + hi) >> 1;
        if (a[mid] < key) lo = mid + 1; else hi = mid;
    }
    return lo;
}

__global__ __launch_bounds__(256) void head_comb(const float* __restrict__ pool,
                                                 const int* __restrict__ batch,
                                                 const float* __restrict__ vec,
                                                 float* __restrict__ comb) {
    int g = blockIdx.x;
    int t = threadIdx.x;
    __shared__ float red[4];
    int lo = lbound(batch, N_NODES, g);
    int hi = lbound(batch, N_NODES, g + 1);
    float c = fmaxf((float)(hi - lo), 1.0f);
    float pm = pool[g * 256 + t] / c;

    float ss = pm * pm;
#pragma unroll
    for (int o = 32; o; o >>= 1) ss += __shfl_down(ss, o);
    if ((t & 63) == 0) red[t >> 6] = ss;
    __syncthreads();
    if (t == 0) {
        float tot = red[0] + red[1] + red[2] + red[3];
        red[0] = 1.0f / fmaxf(sqrtf(tot), 1e-12f);
    }
    __syncthreads();
    comb[g * 512 + t] = pm * red[0];
    comb[g * 512 + 256 + t] = vec[g * 256 + t];
}

// ---------------- head stage 2: z1[g][o] = relu(comb[g]·cW1t[o] + cb1[o]), wave per (g,o) ----------------
__global__ __launch_bounds__(256) void head_z1(const float* __restrict__ comb,
                                               const float* __restrict__ cW1t,
                                               const float* __restrict__ cb1,
                                               float* __restrict__ z1) {
    int wid = (blockIdx.x * 256 + threadIdx.x) >> 6;  // 0..16383
    int lane = threadIdx.x & 63;
    int g = wid >> 8;
    int o = wid & 255;
    const float4* ca = (const float4*)(comb + g * 512);
    const float4* wa = (const float4*)(cW1t + (size_t)o * 512);
    float s = 0.0f;
#pragma unroll
    for (int r = 0; r < 2; r++) {
        float4 c4 = ca[lane * 2 + r];
        float4 w4 = wa[lane * 2 + r];
        s += c4.x * w4.x + c4.y * w4.y + c4.z * w4.z + c4.w * w4.w;
    }
#pragma unroll
    for (int off = 32; off; off >>= 1) s += __shfl_down(s, off);
    if (lane == 0) z1[g * 256 + o] = fmaxf(s + cb1[o], 0.0f);
}

// ---------------- head stage 3: z2 = relu(z1@cW2+cb2); out = sigmoid(z2@cW3+cb3) ----------------
__global__ __launch_bounds__(256) void head_z2z3(const float* __restrict__ z1,
                                                 const float* __restrict__ cW2t,
                                                 const float* __restrict__ cb2,
                                                 const float* __restrict__ cW3,
                                                 const float* __restrict__ cb3,
                                                 float* __restrict__ out) {
    int g = blockIdx.x;
    int t = threadIdx.x;
    int j = t >> 2;   // output 0..63
    int q = t & 3;    // quarter of the 256-dot
    __shared__ float part[256];
    __shared__ float z2s[64];
    const float* z = z1 + g * 256;
    const float* w = cW2t + (size_t)j * 256;
    float s = 0.0f;
#pragma unroll
    for (int i = q * 64; i < q * 64 + 64; i += 4) {
        float4 zv = *(const float4*)(z + i);
        float4 wv = *(const float4*)(w + i);
        s += zv.x * wv.x + zv.y * wv.y + zv.z * wv.z + zv.w * wv.w;
    }
    part[t] = s;
    __syncthreads();
    if (q == 0) {
        float v = part[j * 4] + part[j * 4 + 1] + part[j * 4 + 2] + part[j * 4 + 3] + cb2[j];
        z2s[j] = fmaxf(v, 0.0f);
    }
    __syncthreads();
    if (t < 64) {
        float p = z2s[t] * cW3[t];
#pragma unroll
        for (int off = 32; off; off >>= 1) p += __shfl_down(p, off);
        if (t == 0) out[g] = 1.0f / (1.0f + expf(-(p + cb3[0])));
    }
}

extern "C" void kernel_launch(void* const* d_in, const int* in_sizes, int n_in,
                              void* d_out, int out_size, void* d_ws, size_t ws_size,
                              hipStream_t stream) {
    const float* x   = (const float*)d_in[0];
    const int*   ei  = (const int*)d_in[1];
    const int*   bat = (const int*)d_in[2];
    const float* vec = (const float*)d_in[3];
    const float* W1 = (const float*)d_in[4];
    const float* b1 = (const float*)d_in[5];
    const float* W2 = (const float*)d_in[6];
    const float* b2 = (const float*)d_in[7];
    const float* W3 = (const float*)d_in[8];
    const float* b3 = (const float*)d_in[9];
    const float* W4 = (const float*)d_in[10];
    const float* b4 = (const float*)d_in[11];
    const float* cW1 = (const float*)d_in[12];
    const float* cb1 = (const float*)d_in[13];
    const float* cW2 = (const float*)d_in[14];
    const float* cb2 = (const float*)d_in[15];
    const float* cW3 = (const float*)d_in[16];
    const float* cb3 = (const float*)d_in[17];

    const int* srcI = ei;
    const int* dstI = ei + N_EDGES;

    char* base = (char*)d_ws;
    float* dis      = (float*)base;            base += N_NODES * 4;
    int*   degc     = (int*)base;              base += N_NODES * 4;
    int*   off      = (int*)base;              base += (N_NODES + 1) * 4;
    int*   fc       = (int*)base;              base += N_NODES * 4 + 4;
    int*   csr_src  = (int*)base;              base += N_EDGES * 4;
    float* csr_w    = (float*)base;            base += N_EDGES * 4;
    float* pool     = (float*)base;            base += NGRAPH * 256 * 4;
    float* comb     = (float*)base;            base += NGRAPH * 512 * 4;
    float* z1       = (float*)base;            base += NGRAPH * 256 * 4;
    float* cW1t     = (float*)base;            base += 512 * 256 * 4;
    float* cW2t     = (float*)base;            base += 256 * 64 * 4;
    unsigned short* xb   = (unsigned short*)base;  base += (size_t)N_NODES * 1280 * 2;  // aliased by agg4 later
    unsigned short* W1t  = (unsigned short*)base;  base += 512 * 1280 * 2;
    unsigned short* W2t  = (unsigned short*)base;  base += 512 * 512 * 2;
    unsigned short* W3t  = (unsigned short*)base;  base += 512 * 512 * 2;
    unsigned short* W4t  = (unsigned short*)base;  base += 256 * 512 * 2;
    unsigned short* h    = (unsigned short*)base;  base += (size_t)MPAD * 512 * 2;
    unsigned short* aggb = (unsigned short*)base;  base += (size_t)N_NODES * 512 * 2;
    float* agg4 = (float*)xb;  // alias: xb dead after GEMM1, agg4 written by gather4

    // ---- conversions ----
    conv_bf16<<<(N_NODES * 1280 / 4 + 255) / 256, 256, 0, stream>>>((const float4*)x, (u16x4*)xb, N_NODES * 1280 / 4);
    conv_transpose_w<<<dim3(1280 / 32, 512 / 32), 256, 0, stream>>>(W1, W1t, 1280, 512);
    conv_transpose_w<<<dim3(512 / 32, 512 / 32), 256, 0, stream>>>(W2, W2t, 512, 512);
    conv_transpose_w<<<dim3(512 / 32, 512 / 32), 256, 0, stream>>>(W3, W3t, 512, 512);
    conv_transpose_w<<<dim3(512 / 32, 256 / 32), 256, 0, stream>>>(W4, W4t, 512, 256);
    transpose_f32<<<dim3(512 / 32, 256 / 32), 256, 0, stream>>>(cW1, cW1t, 512, 256);
    transpose_f32<<<dim3(256 / 32, 64 / 32), 256, 0, stream>>>(cW2, cW2t, 256, 64);

    // ---- CSR build ----
    zero_i32<<<(N_NODES + 255) / 256, 256, 0, stream>>>(degc, N_NODES);
    zero_i32<<<(N_NODES + 255) / 256, 256, 0, stream>>>(fc, N_NODES);
    deg_count<<<(N_EDGES + 255) / 256, 256, 0, stream>>>(dstI, degc, N_EDGES);
    deg_fin<<<(N_NODES + 255) / 256, 256, 0, stream>>>(degc, dis, N_NODES);
    scan_offsets<<<1, 1024, 0, stream>>>(degc, off, N_NODES);
    csr_fill<<<(N_EDGES + 255) / 256, 256, 0, stream>>>(srcI, dstI, off, fc, dis, csr_src, csr_w, N_EDGES);

    // ---- layer 1 ----
    gemm_bf16<<<dim3(512 / 128, MPAD / 128), 256, 0, stream>>>(xb, W1t, h, 1280, 512);
    gather_nodes<512, true, true><<<N_NODES, 128, 0, stream>>>(h, off, csr_src, csr_w, dis,
                                                               (const float4*)b1, aggb);
    // ---- layer 2 ----
    gemm_bf16<<<dim3(512 / 128, MPAD / 128), 256, 0, stream>>>(aggb, W2t, h, 512, 512);
    gather_nodes<512, true, true><<<N_NODES, 128, 0, stream>>>(h, off, csr_src, csr_w, dis,
                                                               (const float4*)b2, aggb);
    // ---- layer 3 ----
    gemm_bf16<<<dim3(512 / 128, MPAD / 128), 256, 0, stream>>>(aggb, W3t, h, 512, 512);
    gather_nodes<512, true, true><<<N_NODES, 128, 0, stream>>>(h, off, csr_src, csr_w, dis,
                                                               (const float4*)b3, aggb);
    // ---- layer 4 (no relu, fp32 out) ----
    gemm_bf16<<<dim3(256 / 128, MPAD / 128), 256, 0, stream>>>(aggb, W4t, h, 512, 256);
    gather_nodes<256, false, false><<<N_NODES, 64, 0, stream>>>(h, off, csr_src, csr_w, dis,
                                                                (const float4*)b4, agg4);

    // ---- pooling + head ----
    zero_f32<<<(NGRAPH * 256 + 255) / 256, 256, 0, stream>>>(pool, NGRAPH * 256);
    pool_partial<<<(N_NODES + PCHUNK - 1) / PCHUNK, 256, 0, stream>>>(agg4, bat, pool);
    head_comb<<<NGRAPH, 256, 0, stream>>>(pool, bat, vec, comb);
    head_z1<<<4096, 256, 0, stream>>>(comb, cW1t, cb1, z1);
    head_z2z3<<<NGRAPH, 256, 0, stream>>>(z1, cW2t, cb2, cW3, cb3, (float*)d_out);
}

// Round 10
// 399.524 us; speedup vs baseline: 1.1194x; 1.0349x over previous
//
#include <hip/hip_runtime.h>
#include <hip/hip_bf16.h>

// ToxDL GCN, round 7 (resubmit x2): GEMM retile (64x128, more blocks) + LDS XOR swizzle
// (pre-swizzled global source for global_load_lds, swizzled ds_read slots).
// Rest identical to round 6 (wave-parallel head, chunked pooling, CSR gather).

#define N_NODES 10000
#define N_EDGES 160000
#define NGRAPH  64
#define MPAD    10112   // 158*64
#define PCHUNK  16

typedef __attribute__((ext_vector_type(8))) short short8;
typedef __attribute__((ext_vector_type(4))) float f32x4;
typedef __attribute__((ext_vector_type(4))) unsigned short u16x4;

__device__ __forceinline__ unsigned short f2bf(float f) {
    unsigned u = __float_as_uint(f);
    return (unsigned short)((u + 0x7FFFu + ((u >> 16) & 1u)) >> 16);
}
__device__ __forceinline__ float bf2f(unsigned short u) {
    return __uint_as_float(((unsigned)u) << 16);
}
__device__ __forceinline__ void gl_lds16(const void* g, void* l) {
    __builtin_amdgcn_global_load_lds(
        (const __attribute__((address_space(1))) unsigned*)g,
        (__attribute__((address_space(3))) unsigned*)l, 16, 0, 0);
}

// ---------------- utility ----------------
__global__ __launch_bounds__(256) void zero_i32(int* p, int n) {
    int i = blockIdx.x * 256 + threadIdx.x;
    if (i < n) p[i] = 0;
}
__global__ __launch_bounds__(256) void zero_f32(float* p, int n) {
    int i = blockIdx.x * 256 + threadIdx.x;
    if (i < n) p[i] = 0.0f;
}

// ---------------- convert fp32 -> bf16 (flat, 4/thread) ----------------
__global__ __launch_bounds__(256) void conv_bf16(const float4* __restrict__ in,
                                                 u16x4* __restrict__ out, int n4) {
    int i = blockIdx.x * 256 + threadIdx.x;
    if (i >= n4) return;
    float4 v = in[i];
    u16x4 o;
    o.x = f2bf(v.x); o.y = f2bf(v.y); o.z = f2bf(v.z); o.w = f2bf(v.w);
    out[i] = o;
}

// ---------------- W[K][N] fp32 -> Wt[N][K] bf16 ----------------
__global__ __launch_bounds__(256) void conv_transpose_w(const float* __restrict__ W,
                                                        unsigned short* __restrict__ Wt,
                                                        int K, int N) {
    __shared__ float t[32][33];
    int k0 = blockIdx.x * 32, n0 = blockIdx.y * 32;
    int tx = threadIdx.x & 31, ty = threadIdx.x >> 5;  // ty 0..7
#pragma unroll
    for (int i = 0; i < 4; i++)
        t[ty + i * 8][tx] = W[(size_t)(k0 + ty + i * 8) * N + n0 + tx];
    __syncthreads();
#pragma unroll
    for (int i = 0; i < 4; i++)
        Wt[(size_t)(n0 + ty + i * 8) * K + k0 + tx] = f2bf(t[tx][ty + i * 8]);
}

// ---------------- W[K][N] fp32 -> Wt[N][K] fp32 (head weights) ----------------
__global__ __launch_bounds__(256) void transpose_f32(const float* __restrict__ W,
                                                     float* __restrict__ Wt,
                                                     int K, int N) {
    __shared__ float t[32][33];
    int k0 = blockIdx.x * 32, n0 = blockIdx.y * 32;
    int tx = threadIdx.x & 31, ty = threadIdx.x >> 5;
#pragma unroll
    for (int i = 0; i < 4; i++)
        t[ty + i * 8][tx] = W[(size_t)(k0 + ty + i * 8) * N + n0 + tx];
    __syncthreads();
#pragma unroll
    for (int i = 0; i < 4; i++)
        Wt[(size_t)(n0 + ty + i * 8) * K + k0 + tx] = t[tx][ty + i * 8];
}

// ---------------- CSR build ----------------
__global__ __launch_bounds__(256) void deg_count(const int* __restrict__ dst, int* __restrict__ degc, int E) {
    int e = blockIdx.x * 256 + threadIdx.x;
    if (e < E) atomicAdd(&degc[dst[e]], 1);
}
__global__ __launch_bounds__(256) void deg_fin(const int* __restrict__ degc, float* __restrict__ dis, int n) {
    int i = blockIdx.x * 256 + threadIdx.x;
    if (i < n) dis[i] = 1.0f / sqrtf((float)(degc[i] + 1));
}
__global__ __launch_bounds__(1024) void scan_offsets(const int* __restrict__ cnt,
                                                     int* __restrict__ off, int n) {
    __shared__ int buf[1024];
    __shared__ int carry;
    int t = threadIdx.x;
    if (t == 0) { carry = 0; off[0] = 0; }
    __syncthreads();
    for (int base = 0; base < n; base += 1024) {
        int v = (base + t < n) ? cnt[base + t] : 0;
        buf[t] = v;
        __syncthreads();
#pragma unroll
        for (int o = 1; o < 1024; o <<= 1) {
            int add = (t >= o) ? buf[t - o] : 0;
            __syncthreads();
            buf[t] += add;
            __syncthreads();
        }
        if (base + t < n) off[base + t + 1] = buf[t] + carry;
        __syncthreads();
        if (t == 0) carry += buf[1023];
        __syncthreads();
    }
}
__global__ __launch_bounds__(256) void csr_fill(const int* __restrict__ srcI,
                                                const int* __restrict__ dstI,
                                                const int* __restrict__ off,
                                                int* __restrict__ fc,
                                                const float* __restrict__ dis,
                                                int* __restrict__ csr_src,
                                                float* __restrict__ csr_w, int E) {
    int e = blockIdx.x * 256 + threadIdx.x;
    if (e >= E) return;
    int d = dstI[e];
    int s = srcI[e];
    int pos = off[d] + atomicAdd(&fc[d], 1);
    csr_src[pos] = s;
    csr_w[pos] = dis[s];
}

// ---------------- bf16 MFMA GEMM: C[MPAD][N](bf16) = A[<=10000][K](bf16) @ Bt[N][K]^T ----------------
// BM=64, BN=128, BK=64; 256 threads (4 waves as 2Mx2N, each 32x64 output).
// LDS XOR swizzle: slot q of row r holds global 16B-chunk q^(r&7); staged via
// pre-swizzled global source (global_load_lds dest stays linear), read with same XOR.
__global__ __launch_bounds__(256) void gemm_bf16(const unsigned short* __restrict__ A,
                                                 const unsigned short* __restrict__ Bt,
                                                 unsigned short* __restrict__ C,
                                                 int K, int N) {
    __shared__ short lA[64 * 64];
    __shared__ short lB[128 * 64];
    int tid = threadIdx.x;
    int lane = tid & 63;
    int wave = tid >> 6;
    int rm = blockIdx.y, cn = blockIdx.x;
    int wr = wave >> 1, wc = wave & 1;

    f32x4 acc[2][4];
#pragma unroll
    for (int m = 0; m < 2; m++)
#pragma unroll
        for (int n = 0; n < 4; n++) acc[m][n] = (f32x4){0.f, 0.f, 0.f, 0.f};

    int lrow = lane >> 3;                         // row within 8-row segment
    int lcs = ((lane & 7) ^ (lrow & 7)) * 8;      // pre-swizzled source chunk (shorts)

    for (int k0 = 0; k0 < K; k0 += 64) {
        __syncthreads();
#pragma unroll
        for (int i = 0; i < 2; i++) {             // A: 64 rows = 8 segments
            int s = wave * 2 + i;
            int row = rm * 64 + s * 8 + lrow;
            if (row > N_NODES - 1) row = N_NODES - 1;   // tail clamp (dup rows, never read)
            gl_lds16(A + (size_t)row * K + k0 + lcs, &lA[s * 512]);
        }
#pragma unroll
        for (int i = 0; i < 4; i++) {             // B: 128 rows = 16 segments
            int s = wave * 4 + i;
            int row = cn * 128 + s * 8 + lrow;
            gl_lds16(Bt + (size_t)row * K + k0 + lcs, &lB[s * 512]);
        }
        __syncthreads();
#pragma unroll
        for (int kk = 0; kk < 64; kk += 32) {
            int cbase = (kk >> 3) + (lane >> 4);  // 16B-chunk index within row
            short8 a[2], b[4];
#pragma unroll
            for (int m = 0; m < 2; m++) {
                int r = wr * 32 + m * 16 + (lane & 15);
                a[m] = *(const short8*)&lA[r * 64 + (cbase ^ (r & 7)) * 8];
            }
#pragma unroll
            for (int n = 0; n < 4; n++) {
                int r = wc * 64 + n * 16 + (lane & 15);
                b[n] = *(const short8*)&lB[r * 64 + (cbase ^ (r & 7)) * 8];
            }
#pragma unroll
            for (int m = 0; m < 2; m++)
#pragma unroll
                for (int n = 0; n < 4; n++)
                    acc[m][n] = __builtin_amdgcn_mfma_f32_16x16x32_bf16(a[m], b[n], acc[m][n], 0, 0, 0);
        }
    }
    int r0 = rm * 64 + wr * 32 + (lane >> 4) * 4;
    int c0 = cn * 128 + wc * 64 + (lane & 15);
#pragma unroll
    for (int m = 0; m < 2; m++)
#pragma unroll
        for (int n = 0; n < 4; n++)
#pragma unroll
            for (int j = 0; j < 4; j++)
                C[(size_t)(r0 + m * 16 + j) * N + c0 + n * 16] = f2bf(acc[m][n][j]);
}

// ---------------- per-node CSR gather, fused self-loop + bias (+relu) ----------------
template<int D, bool RELU, bool OUTBF>
__global__ __launch_bounds__(D / 4) void gather_nodes(const unsigned short* __restrict__ h,
                                                      const int* __restrict__ off,
                                                      const int* __restrict__ csr_src,
                                                      const float* __restrict__ csr_w,
                                                      const float* __restrict__ dis,
                                                      const float4* __restrict__ bias,
                                                      void* __restrict__ outp) {
    int n = blockIdx.x;
    int f = threadIdx.x;
    float dn = dis[n];
    u16x4 hv = ((const u16x4*)(h + (size_t)n * D))[f];
    float ax = dn * bf2f(hv.x), ay = dn * bf2f(hv.y), az = dn * bf2f(hv.z), aw = dn * bf2f(hv.w);
    int kb = off[n], ke = off[n + 1];
    for (int k = kb; k < ke; k++) {
        int s = csr_src[k];
        float w = csr_w[k];
        u16x4 v = ((const u16x4*)(h + (size_t)s * D))[f];
        ax += w * bf2f(v.x); ay += w * bf2f(v.y); az += w * bf2f(v.z); aw += w * bf2f(v.w);
    }
    float4 bb = bias[f];
    float ox = ax * dn + bb.x, oy = ay * dn + bb.y, oz = az * dn + bb.z, ow = aw * dn + bb.w;
    if (RELU) {
        ox = fmaxf(ox, 0.f); oy = fmaxf(oy, 0.f); oz = fmaxf(oz, 0.f); ow = fmaxf(ow, 0.f);
    }
    if (OUTBF) {
        u16x4 o; o.x = f2bf(ox); o.y = f2bf(oy); o.z = f2bf(oz); o.w = f2bf(ow);
        ((u16x4*)outp)[(size_t)n * (D / 4) + f] = o;
    } else {
        ((float4*)outp)[(size_t)n * (D / 4) + f] = make_float4(ox, oy, oz, ow);
    }
}

// ---------------- parallel pooling: chunked segment-sum (batch sorted) ----------------
__global__ __launch_bounds__(256) void pool_partial(const float* __restrict__ agg,
                                                    const int* __restrict__ batch,
                                                    float* __restrict__ pool) {
    int c0 = blockIdx.x * PCHUNK;
    int t = threadIdx.x;
    int end = c0 + PCHUNK;
    if (end > N_NODES) end = N_NODES;
    float acc = 0.0f;
    int cur = batch[c0];
    for (int n = c0; n < end; n++) {
        int g = batch[n];
        if (g != cur) {
            atomicAdd(&pool[cur * 256 + t], acc);
            acc = 0.0f;
            cur = g;
        }
        acc += agg[(size_t)n * 256 + t];
    }
    atomicAdd(&pool[cur * 256 + t], acc);
}

// ---------------- head stage 1: mean + L2-normalize + concat -> comb[64][512] ----------------
__device__ __forceinline__ int lbound(const int* __restrict__ a, int n, int key) {
    int lo = 0, hi = n;
    while (lo < hi) {
        int mid = (lo + hi) >> 1;
        if (a[mid] < key) lo = mid + 1; else hi = mid;
    }
    return lo;
}

__global__ __launch_bounds__(256) void head_comb(const float* __restrict__ pool,
                                                 const int* __restrict__ batch,
                                                 const float* __restrict__ vec,
                                                 float* __restrict__ comb) {
    int g = blockIdx.x;
    int t = threadIdx.x;
    __shared__ float red[4];
    int lo = lbound(batch, N_NODES, g);
    int hi = lbound(batch, N_NODES, g + 1);
    float c = fmaxf((float)(hi - lo), 1.0f);
    float pm = pool[g * 256 + t] / c;

    float ss = pm * pm;
#pragma unroll
    for (int o = 32; o; o >>= 1) ss += __shfl_down(ss, o);
    if ((t & 63) == 0) red[t >> 6] = ss;
    __syncthreads();
    if (t == 0) {
        float tot = red[0] + red[1] + red[2] + red[3];
        red[0] = 1.0f / fmaxf(sqrtf(tot), 1e-12f);
    }
    __syncthreads();
    comb[g * 512 + t] = pm * red[0];
    comb[g * 512 + 256 + t] = vec[g * 256 + t];
}

// ---------------- head stage 2: z1[g][o] = relu(comb[g]·cW1t[o] + cb1[o]), wave per (g,o) ----------------
__global__ __launch_bounds__(256) void head_z1(const float* __restrict__ comb,
                                               const float* __restrict__ cW1t,
                                               const float* __restrict__ cb1,
                                               float* __restrict__ z1) {
    int wid = (blockIdx.x * 256 + threadIdx.x) >> 6;  // 0..16383
    int lane = threadIdx.x & 63;
    int g = wid >> 8;
    int o = wid & 255;
    const float4* ca = (const float4*)(comb + g * 512);
    const float4* wa = (const float4*)(cW1t + (size_t)o * 512);
    float s = 0.0f;
#pragma unroll
    for (int r = 0; r < 2; r++) {
        float4 c4 = ca[lane * 2 + r];
        float4 w4 = wa[lane * 2 + r];
        s += c4.x * w4.x + c4.y * w4.y + c4.z * w4.z + c4.w * w4.w;
    }
#pragma unroll
    for (int off = 32; off; off >>= 1) s += __shfl_down(s, off);
    if (lane == 0) z1[g * 256 + o] = fmaxf(s + cb1[o], 0.0f);
}

// ---------------- head stage 3: z2 = relu(z1@cW2+cb2); out = sigmoid(z2@cW3+cb3) ----------------
__global__ __launch_bounds__(256) void head_z2z3(const float* __restrict__ z1,
                                                 const float* __restrict__ cW2t,
                                                 const float* __restrict__ cb2,
                                                 const float* __restrict__ cW3,
                                                 const float* __restrict__ cb3,
                                                 float* __restrict__ out) {
    int g = blockIdx.x;
    int t = threadIdx.x;
    int j = t >> 2;   // output 0..63
    int q = t & 3;    // quarter of the 256-dot
    __shared__ float part[256];
    __shared__ float z2s[64];
    const float* z = z1 + g * 256;
    const float* w = cW2t + (size_t)j * 256;
    float s = 0.0f;
#pragma unroll
    for (int i = q * 64; i < q * 64 + 64; i += 4) {
        float4 zv = *(const float4*)(z + i);
        float4 wv = *(const float4*)(w + i);
        s += zv.x * wv.x + zv.y * wv.y + zv.z * wv.z + zv.w * wv.w;
    }
    part[t] = s;
    __syncthreads();
    if (q == 0) {
        float v = part[j * 4] + part[j * 4 + 1] + part[j * 4 + 2] + part[j * 4 + 3] + cb2[j];
        z2s[j] = fmaxf(v, 0.0f);
    }
    __syncthreads();
    if (t < 64) {
        float p = z2s[t] * cW3[t];
#pragma unroll
        for (int off = 32; off; off >>= 1) p += __shfl_down(p, off);
        if (t == 0) out[g] = 1.0f / (1.0f + expf(-(p + cb3[0])));
    }
}

extern "C" void kernel_launch(void* const* d_in, const int* in_sizes, int n_in,
                              void* d_out, int out_size, void* d_ws, size_t ws_size,
                              hipStream_t stream) {
    const float* x   = (const float*)d_in[0];
    const int*   ei  = (const int*)d_in[1];
    const int*   bat = (const int*)d_in[2];
    const float* vec = (const float*)d_in[3];
    const float* W1 = (const float*)d_in[4];
    const float* b1 = (const float*)d_in[5];
    const float* W2 = (const float*)d_in[6];
    const float* b2 = (const float*)d_in[7];
    const float* W3 = (const float*)d_in[8];
    const float* b3 = (const float*)d_in[9];
    const float* W4 = (const float*)d_in[10];
    const float* b4 = (const float*)d_in[11];
    const float* cW1 = (const float*)d_in[12];
    const float* cb1 = (const float*)d_in[13];
    const float* cW2 = (const float*)d_in[14];
    const float* cb2 = (const float*)d_in[15];
    const float* cW3 = (const float*)d_in[16];
    const float* cb3 = (const float*)d_in[17];

    const int* srcI = ei;
    const int* dstI = ei + N_EDGES;

    char* base = (char*)d_ws;
    float* dis      = (float*)base;            base += N_NODES * 4;
    int*   degc     = (int*)base;              base += N_NODES * 4;
    int*   off      = (int*)base;              base += (N_NODES + 1) * 4;
    int*   fc       = (int*)base;              base += N_NODES * 4 + 4;
    int*   csr_src  = (int*)base;              base += N_EDGES * 4;
    float* csr_w    = (float*)base;            base += N_EDGES * 4;
    float* pool     = (float*)base;            base += NGRAPH * 256 * 4;
    float* comb     = (float*)base;            base += NGRAPH * 512 * 4;
    float* z1       = (float*)base;            base += NGRAPH * 256 * 4;
    float* cW1t     = (float*)base;            base += 512 * 256 * 4;
    float* cW2t     = (float*)base;            base += 256 * 64 * 4;
    unsigned short* xb   = (unsigned short*)base;  base += (size_t)N_NODES * 1280 * 2;  // aliased by agg4 later
    unsigned short* W1t  = (unsigned short*)base;  base += 512 * 1280 * 2;
    unsigned short* W2t  = (unsigned short*)base;  base += 512 * 512 * 2;
    unsigned short* W3t  = (unsigned short*)base;  base += 512 * 512 * 2;
    unsigned short* W4t  = (unsigned short*)base;  base += 256 * 512 * 2;
    unsigned short* h    = (unsigned short*)base;  base += (size_t)MPAD * 512 * 2;
    unsigned short* aggb = (unsigned short*)base;  base += (size_t)N_NODES * 512 * 2;
    float* agg4 = (float*)xb;  // alias: xb dead after GEMM1, agg4 written by gather4

    // ---- conversions ----
    conv_bf16<<<(N_NODES * 1280 / 4 + 255) / 256, 256, 0, stream>>>((const float4*)x, (u16x4*)xb, N_NODES * 1280 / 4);
    conv_transpose_w<<<dim3(1280 / 32, 512 / 32), 256, 0, stream>>>(W1, W1t, 1280, 512);
    conv_transpose_w<<<dim3(512 / 32, 512 / 32), 256, 0, stream>>>(W2, W2t, 512, 512);
    conv_transpose_w<<<dim3(512 / 32, 512 / 32), 256, 0, stream>>>(W3, W3t, 512, 512);
    conv_transpose_w<<<dim3(512 / 32, 256 / 32), 256, 0, stream>>>(W4, W4t, 512, 256);
    transpose_f32<<<dim3(512 / 32, 256 / 32), 256, 0, stream>>>(cW1, cW1t, 512, 256);
    transpose_f32<<<dim3(256 / 32, 64 / 32), 256, 0, stream>>>(cW2, cW2t, 256, 64);

    // ---- CSR build ----
    zero_i32<<<(N_NODES + 255) / 256, 256, 0, stream>>>(degc, N_NODES);
    zero_i32<<<(N_NODES + 255) / 256, 256, 0, stream>>>(fc, N_NODES);
    deg_count<<<(N_EDGES + 255) / 256, 256, 0, stream>>>(dstI, degc, N_EDGES);
    deg_fin<<<(N_NODES + 255) / 256, 256, 0, stream>>>(degc, dis, N_NODES);
    scan_offsets<<<1, 1024, 0, stream>>>(degc, off, N_NODES);
    csr_fill<<<(N_EDGES + 255) / 256, 256, 0, stream>>>(srcI, dstI, off, fc, dis, csr_src, csr_w, N_EDGES);

    // ---- layer 1 ----
    gemm_bf16<<<dim3(512 / 128, MPAD / 64), 256, 0, stream>>>(xb, W1t, h, 1280, 512);
    gather_nodes<512, true, true><<<N_NODES, 128, 0, stream>>>(h, off, csr_src, csr_w, dis,
                                                               (const float4*)b1, aggb);
    // ---- layer 2 ----
    gemm_bf16<<<dim3(512 / 128, MPAD / 64), 256, 0, stream>>>(aggb, W2t, h, 512, 512);
    gather_nodes<512, true, true><<<N_NODES, 128, 0, stream>>>(h, off, csr_src, csr_w, dis,
                                                               (const float4*)b2, aggb);
    // ---- layer 3 ----
    gemm_bf16<<<dim3(512 / 128, MPAD / 64), 256, 0, stream>>>(aggb, W3t, h, 512, 512);
    gather_nodes<512, true, true><<<N_NODES, 128, 0, stream>>>(h, off, csr_src, csr_w, dis,
                                                               (const float4*)b3, aggb);
    // ---- layer 4 (no relu, fp32 out) ----
    gemm_bf16<<<dim3(256 / 128, MPAD / 64), 256, 0, stream>>>(aggb, W4t, h, 512, 256);
    gather_nodes<256, false, false><<<N_NODES, 64, 0, stream>>>(h, off, csr_src, csr_w, dis,
                                                                (const float4*)b4, agg4);

    // ---- pooling + head ----
    zero_f32<<<(NGRAPH * 256 + 255) / 256, 256, 0, stream>>>(pool, NGRAPH * 256);
    pool_partial<<<(N_NODES + PCHUNK - 1) / PCHUNK, 256, 0, stream>>>(agg4, bat, pool);
    head_comb<<<NGRAPH, 256, 0, stream>>>(pool, bat, vec, comb);
    head_z1<<<4096, 256, 0, stream>>>(comb, cW1t, cb1, z1);
    head_z2z3<<<NGRAPH, 256, 0, stream>>>(z1, cW2t, cb2, cW3, cb3, (float*)d_out);
}

// Round 11
// 356.609 us; speedup vs baseline: 1.2541x; 1.1203x over previous
//
#include <hip/hip_runtime.h>
#include <hip/hip_bf16.h>
#include <type_traits>

// ToxDL GCN, round 10: ILP gather (wave-per-node, 16B loads, 4-wide neighbor
// batching), shuffle-scan CSR build (fused dis), fused transpose launches.
// GEMM identical to round 7 (64x128 tile + XOR swizzle).

#define N_NODES 10000
#define N_EDGES 160000
#define NGRAPH  64
#define MPAD    10112   // 158*64
#define PCHUNK  16

typedef __attribute__((ext_vector_type(8))) short short8;
typedef __attribute__((ext_vector_type(4))) float f32x4;
typedef __attribute__((ext_vector_type(4))) unsigned short u16x4;
typedef __attribute__((ext_vector_type(8))) unsigned short u16x8;

__device__ __forceinline__ unsigned short f2bf(float f) {
    unsigned u = __float_as_uint(f);
    return (unsigned short)((u + 0x7FFFu + ((u >> 16) & 1u)) >> 16);
}
__device__ __forceinline__ float bf2f(unsigned short u) {
    return __uint_as_float(((unsigned)u) << 16);
}
__device__ __forceinline__ void gl_lds16(const void* g, void* l) {
    __builtin_amdgcn_global_load_lds(
        (const __attribute__((address_space(1))) unsigned*)g,
        (__attribute__((address_space(3))) unsigned*)l, 16, 0, 0);
}

// ---------------- utility ----------------
__global__ __launch_bounds__(256) void zero_i32(int* p, int n) {
    int i = blockIdx.x * 256 + threadIdx.x;
    if (i < n) p[i] = 0;
}
__global__ __launch_bounds__(256) void zero_f32(float* p, int n) {
    int i = blockIdx.x * 256 + threadIdx.x;
    if (i < n) p[i] = 0.0f;
}

// ---------------- convert fp32 -> bf16 (flat, 4/thread) ----------------
__global__ __launch_bounds__(256) void conv_bf16(const float4* __restrict__ in,
                                                 u16x4* __restrict__ out, int n4) {
    int i = blockIdx.x * 256 + threadIdx.x;
    if (i >= n4) return;
    float4 v = in[i];
    u16x4 o;
    o.x = f2bf(v.x); o.y = f2bf(v.y); o.z = f2bf(v.z); o.w = f2bf(v.w);
    out[i] = o;
}

// ---------------- all 4 GCN weights: W[K][N] fp32 -> Wt[N][K] bf16, one launch ----------------
__global__ __launch_bounds__(256) void conv_transpose_w4(
        const float* __restrict__ W1, const float* __restrict__ W2,
        const float* __restrict__ W3, const float* __restrict__ W4,
        unsigned short* __restrict__ W1t, unsigned short* __restrict__ W2t,
        unsigned short* __restrict__ W3t, unsigned short* __restrict__ W4t) {
    const float* W; unsigned short* Wt; int K, N;
    switch (blockIdx.z) {
        case 0:  W = W1; Wt = W1t; K = 1280; N = 512; break;
        case 1:  W = W2; Wt = W2t; K = 512;  N = 512; break;
        case 2:  W = W3; Wt = W3t; K = 512;  N = 512; break;
        default: W = W4; Wt = W4t; K = 512;  N = 256; break;
    }
    int k0 = blockIdx.x * 32, n0 = blockIdx.y * 32;
    if (k0 >= K || n0 >= N) return;
    __shared__ float t[32][33];
    int tx = threadIdx.x & 31, ty = threadIdx.x >> 5;  // ty 0..7
#pragma unroll
    for (int i = 0; i < 4; i++)
        t[ty + i * 8][tx] = W[(size_t)(k0 + ty + i * 8) * N + n0 + tx];
    __syncthreads();
#pragma unroll
    for (int i = 0; i < 4; i++)
        Wt[(size_t)(n0 + ty + i * 8) * K + k0 + tx] = f2bf(t[tx][ty + i * 8]);
}

// ---------------- head weights: W[K][N] fp32 -> Wt[N][K] fp32, one launch ----------------
__global__ __launch_bounds__(256) void transpose_f32_2(
        const float* __restrict__ cW1, const float* __restrict__ cW2,
        float* __restrict__ cW1t, float* __restrict__ cW2t) {
    const float* W; float* Wt; int K, N;
    if (blockIdx.z == 0) { W = cW1; Wt = cW1t; K = 512; N = 256; }
    else                 { W = cW2; Wt = cW2t; K = 256; N = 64; }
    int k0 = blockIdx.x * 32, n0 = blockIdx.y * 32;
    if (k0 >= K || n0 >= N) return;
    __shared__ float t[32][33];
    int tx = threadIdx.x & 31, ty = threadIdx.x >> 5;
#pragma unroll
    for (int i = 0; i < 4; i++)
        t[ty + i * 8][tx] = W[(size_t)(k0 + ty + i * 8) * N + n0 + tx];
    __syncthreads();
#pragma unroll
    for (int i = 0; i < 4; i++)
        Wt[(size_t)(n0 + ty + i * 8) * K + k0 + tx] = t[tx][ty + i * 8];
}

// ---------------- CSR build ----------------
__global__ __launch_bounds__(256) void deg_count(const int* __restrict__ dst, int* __restrict__ degc, int E) {
    int e = blockIdx.x * 256 + threadIdx.x;
    if (e < E) atomicAdd(&degc[dst[e]], 1);
}

// exclusive scan over degc -> off[0..n]; also dis[i] = rsqrt(degc[i]+1)
__global__ __launch_bounds__(1024) void scan_offsets(const int* __restrict__ cnt,
                                                     int* __restrict__ off,
                                                     float* __restrict__ dis, int n) {
    __shared__ int wsum[16];
    __shared__ int carry;
    int t = threadIdx.x;
    int wv = t >> 6, ln = t & 63;
    if (t == 0) { carry = 0; off[0] = 0; }
    __syncthreads();
    for (int base = 0; base < n; base += 1024) {
        int idx = base + t;
        int v = (idx < n) ? cnt[idx] : 0;
        if (idx < n) dis[idx] = rsqrtf((float)(v + 1));
        // inclusive scan within wave
#pragma unroll
        for (int o = 1; o < 64; o <<= 1) {
            int u = __shfl_up(v, o);
            if (ln >= o) v += u;
        }
        if (ln == 63) wsum[wv] = v;
        __syncthreads();
        if (wv == 0 && ln < 16) {
            int s = wsum[ln];
#pragma unroll
            for (int o = 1; o < 16; o <<= 1) {
                int u = __shfl_up(s, o);
                if (ln >= o) s += u;
            }
            wsum[ln] = s;
        }
        __syncthreads();
        int add = (wv > 0) ? wsum[wv - 1] : 0;
        int total = wsum[15];
        if (idx < n) off[idx + 1] = v + add + carry;
        __syncthreads();
        if (t == 0) carry += total;
        __syncthreads();
    }
}

__global__ __launch_bounds__(256) void csr_fill(const int* __restrict__ srcI,
                                                const int* __restrict__ dstI,
                                                const int* __restrict__ off,
                                                int* __restrict__ fc,
                                                const float* __restrict__ dis,
                                                int* __restrict__ csr_src,
                                                float* __restrict__ csr_w, int E) {
    int e = blockIdx.x * 256 + threadIdx.x;
    if (e >= E) return;
    int d = dstI[e];
    int s = srcI[e];
    int pos = off[d] + atomicAdd(&fc[d], 1);
    csr_src[pos] = s;
    csr_w[pos] = dis[s];
}

// ---------------- bf16 MFMA GEMM (round-7 version, unchanged) ----------------
__global__ __launch_bounds__(256) void gemm_bf16(const unsigned short* __restrict__ A,
                                                 const unsigned short* __restrict__ Bt,
                                                 unsigned short* __restrict__ C,
                                                 int K, int N) {
    __shared__ short lA[64 * 64];
    __shared__ short lB[128 * 64];
    int tid = threadIdx.x;
    int lane = tid & 63;
    int wave = tid >> 6;
    int rm = blockIdx.y, cn = blockIdx.x;
    int wr = wave >> 1, wc = wave & 1;

    f32x4 acc[2][4];
#pragma unroll
    for (int m = 0; m < 2; m++)
#pragma unroll
        for (int n = 0; n < 4; n++) acc[m][n] = (f32x4){0.f, 0.f, 0.f, 0.f};

    int lrow = lane >> 3;
    int lcs = ((lane & 7) ^ (lrow & 7)) * 8;

    for (int k0 = 0; k0 < K; k0 += 64) {
        __syncthreads();
#pragma unroll
        for (int i = 0; i < 2; i++) {
            int s = wave * 2 + i;
            int row = rm * 64 + s * 8 + lrow;
            if (row > N_NODES - 1) row = N_NODES - 1;
            gl_lds16(A + (size_t)row * K + k0 + lcs, &lA[s * 512]);
        }
#pragma unroll
        for (int i = 0; i < 4; i++) {
            int s = wave * 4 + i;
            int row = cn * 128 + s * 8 + lrow;
            gl_lds16(Bt + (size_t)row * K + k0 + lcs, &lB[s * 512]);
        }
        __syncthreads();
#pragma unroll
        for (int kk = 0; kk < 64; kk += 32) {
            int cbase = (kk >> 3) + (lane >> 4);
            short8 a[2], b[4];
#pragma unroll
            for (int m = 0; m < 2; m++) {
                int r = wr * 32 + m * 16 + (lane & 15);
                a[m] = *(const short8*)&lA[r * 64 + (cbase ^ (r & 7)) * 8];
            }
#pragma unroll
            for (int n = 0; n < 4; n++) {
                int r = wc * 64 + n * 16 + (lane & 15);
                b[n] = *(const short8*)&lB[r * 64 + (cbase ^ (r & 7)) * 8];
            }
#pragma unroll
            for (int m = 0; m < 2; m++)
#pragma unroll
                for (int n = 0; n < 4; n++)
                    acc[m][n] = __builtin_amdgcn_mfma_f32_16x16x32_bf16(a[m], b[n], acc[m][n], 0, 0, 0);
        }
    }
    int r0 = rm * 64 + wr * 32 + (lane >> 4) * 4;
    int c0 = cn * 128 + wc * 64 + (lane & 15);
#pragma unroll
    for (int m = 0; m < 2; m++)
#pragma unroll
        for (int n = 0; n < 4; n++)
#pragma unroll
            for (int j = 0; j < 4; j++)
                C[(size_t)(r0 + m * 16 + j) * N + c0 + n * 16] = f2bf(acc[m][n][j]);
}

// ---------------- wave-per-node CSR gather, 4-wide neighbor ILP ----------------
// 4 waves/block, each wave owns one node; lane covers VPL=D/64 contiguous bf16.
template<int D, bool RELU, bool OUTBF>
__global__ __launch_bounds__(256) void gather_nodes(const unsigned short* __restrict__ h,
                                                    const int* __restrict__ off,
                                                    const int* __restrict__ csr_src,
                                                    const float* __restrict__ csr_w,
                                                    const float* __restrict__ dis,
                                                    const float* __restrict__ bias,
                                                    void* __restrict__ outp) {
    constexpr int VPL = D / 64;
    using uvec = typename std::conditional<VPL == 8, u16x8, u16x4>::type;
    int n = blockIdx.x * 4 + (threadIdx.x >> 6);
    if (n >= N_NODES) return;
    int lane = threadIdx.x & 63;
    const unsigned short* hl = h + (size_t)lane * VPL;
    float dn = dis[n];
    float acc[VPL];
    uvec sv = *(const uvec*)(hl + (size_t)n * D);
#pragma unroll
    for (int j = 0; j < VPL; j++) acc[j] = dn * bf2f(sv[j]);
    int kb = off[n], ke = off[n + 1];
    int k = kb;
    for (; k + 4 <= ke; k += 4) {
        int s0 = csr_src[k + 0], s1 = csr_src[k + 1], s2 = csr_src[k + 2], s3 = csr_src[k + 3];
        float w0 = csr_w[k + 0], w1 = csr_w[k + 1], w2 = csr_w[k + 2], w3 = csr_w[k + 3];
        uvec v0 = *(const uvec*)(hl + (size_t)s0 * D);
        uvec v1 = *(const uvec*)(hl + (size_t)s1 * D);
        uvec v2 = *(const uvec*)(hl + (size_t)s2 * D);
        uvec v3 = *(const uvec*)(hl + (size_t)s3 * D);
#pragma unroll
        for (int j = 0; j < VPL; j++)
            acc[j] += w0 * bf2f(v0[j]) + w1 * bf2f(v1[j]) + w2 * bf2f(v2[j]) + w3 * bf2f(v3[j]);
    }
    for (; k < ke; k++) {
        int s = csr_src[k];
        float w = csr_w[k];
        uvec v = *(const uvec*)(hl + (size_t)s * D);
#pragma unroll
        for (int j = 0; j < VPL; j++) acc[j] += w * bf2f(v[j]);
    }
#pragma unroll
    for (int j = 0; j < VPL; j++) {
        float o = acc[j] * dn + bias[lane * VPL + j];
        if (RELU) o = fmaxf(o, 0.0f);
        acc[j] = o;
    }
    if (OUTBF) {
        uvec ov;
#pragma unroll
        for (int j = 0; j < VPL; j++) ov[j] = f2bf(acc[j]);
        *(uvec*)((unsigned short*)outp + (size_t)n * D + lane * VPL) = ov;
    } else {
#pragma unroll
        for (int j = 0; j < VPL; j += 4)
            *(float4*)((float*)outp + (size_t)n * D + lane * VPL + j) =
                make_float4(acc[j], acc[j + 1], acc[j + 2], acc[j + 3]);
    }
}

// ---------------- parallel pooling: chunked segment-sum (batch sorted) ----------------
__global__ __launch_bounds__(256) void pool_partial(const float* __restrict__ agg,
                                                    const int* __restrict__ batch,
                                                    float* __restrict__ pool) {
    int c0 = blockIdx.x * PCHUNK;
    int t = threadIdx.x;
    int end = c0 + PCHUNK;
    if (end > N_NODES) end = N_NODES;
    float acc = 0.0f;
    int cur = batch[c0];
    for (int n = c0; n < end; n++) {
        int g = batch[n];
        if (g != cur) {
            atomicAdd(&pool[cur * 256 + t], acc);
            acc = 0.0f;
            cur = g;
        }
        acc += agg[(size_t)n * 256 + t];
    }
    atomicAdd(&pool[cur * 256 + t], acc);
}

// ---------------- head ----------------
__device__ __forceinline__ int lbound(const int* __restrict__ a, int n, int key) {
    int lo = 0, hi = n;
    while (lo < hi) {
        int mid = (lo + hi) >> 1;
        if (a[mid] < key) lo = mid + 1; else hi = mid;
    }
    return lo;
}

__global__ __launch_bounds__(256) void head_comb(const float* __restrict__ pool,
                                                 const int* __restrict__ batch,
                                                 const float* __restrict__ vec,
                                                 float* __restrict__ comb) {
    int g = blockIdx.x;
    int t = threadIdx.x;
    __shared__ float red[4];
    int lo = lbound(batch, N_NODES, g);
    int hi = lbound(batch, N_NODES, g + 1);
    float c = fmaxf((float)(hi - lo), 1.0f);
    float pm = pool[g * 256 + t] / c;

    float ss = pm * pm;
#pragma unroll
    for (int o = 32; o; o >>= 1) ss += __shfl_down(ss, o);
    if ((t & 63) == 0) red[t >> 6] = ss;
    __syncthreads();
    if (t == 0) {
        float tot = red[0] + red[1] + red[2] + red[3];
        red[0] = 1.0f / fmaxf(sqrtf(tot), 1e-12f);
    }
    __syncthreads();
    comb[g * 512 + t] = pm * red[0];
    comb[g * 512 + 256 + t] = vec[g * 256 + t];
}

__global__ __launch_bounds__(256) void head_z1(const float* __restrict__ comb,
                                               const float* __restrict__ cW1t,
                                               const float* __restrict__ cb1,
                                               float* __restrict__ z1) {
    int wid = (blockIdx.x * 256 + threadIdx.x) >> 6;
    int lane = threadIdx.x & 63;
    int g = wid >> 8;
    int o = wid & 255;
    const float4* ca = (const float4*)(comb + g * 512);
    const float4* wa = (const float4*)(cW1t + (size_t)o * 512);
    float s = 0.0f;
#pragma unroll
    for (int r = 0; r < 2; r++) {
        float4 c4 = ca[lane * 2 + r];
        float4 w4 = wa[lane * 2 + r];
        s += c4.x * w4.x + c4.y * w4.y + c4.z * w4.z + c4.w * w4.w;
    }
#pragma unroll
    for (int off = 32; off; off >>= 1) s += __shfl_down(s, off);
    if (lane == 0) z1[g * 256 + o] = fmaxf(s + cb1[o], 0.0f);
}

__global__ __launch_bounds__(256) void head_z2z3(const float* __restrict__ z1,
                                                 const float* __restrict__ cW2t,
                                                 const float* __restrict__ cb2,
                                                 const float* __restrict__ cW3,
                                                 const float* __restrict__ cb3,
                                                 float* __restrict__ out) {
    int g = blockIdx.x;
    int t = threadIdx.x;
    int j = t >> 2;
    int q = t & 3;
    __shared__ float part[256];
    __shared__ float z2s[64];
    const float* z = z1 + g * 256;
    const float* w = cW2t + (size_t)j * 256;
    float s = 0.0f;
#pragma unroll
    for (int i = q * 64; i < q * 64 + 64; i += 4) {
        float4 zv = *(const float4*)(z + i);
        float4 wv = *(const float4*)(w + i);
        s += zv.x * wv.x + zv.y * wv.y + zv.z * wv.z + zv.w * wv.w;
    }
    part[t] = s;
    __syncthreads();
    if (q == 0) {
        float v = part[j * 4] + part[j * 4 + 1] + part[j * 4 + 2] + part[j * 4 + 3] + cb2[j];
        z2s[j] = fmaxf(v, 0.0f);
    }
    __syncthreads();
    if (t < 64) {
        float p = z2s[t] * cW3[t];
#pragma unroll
        for (int off = 32; off; off >>= 1) p += __shfl_down(p, off);
        if (t == 0) out[g] = 1.0f / (1.0f + expf(-(p + cb3[0])));
    }
}

extern "C" void kernel_launch(void* const* d_in, const int* in_sizes, int n_in,
                              void* d_out, int out_size, void* d_ws, size_t ws_size,
                              hipStream_t stream) {
    const float* x   = (const float*)d_in[0];
    const int*   ei  = (const int*)d_in[1];
    const int*   bat = (const int*)d_in[2];
    const float* vec = (const float*)d_in[3];
    const float* W1 = (const float*)d_in[4];
    const float* b1 = (const float*)d_in[5];
    const float* W2 = (const float*)d_in[6];
    const float* b2 = (const float*)d_in[7];
    const float* W3 = (const float*)d_in[8];
    const float* b3 = (const float*)d_in[9];
    const float* W4 = (const float*)d_in[10];
    const float* b4 = (const float*)d_in[11];
    const float* cW1 = (const float*)d_in[12];
    const float* cb1 = (const float*)d_in[13];
    const float* cW2 = (const float*)d_in[14];
    const float* cb2 = (const float*)d_in[15];
    const float* cW3 = (const float*)d_in[16];
    const float* cb3 = (const float*)d_in[17];

    const int* srcI = ei;
    const int* dstI = ei + N_EDGES;

    char* base = (char*)d_ws;
    int*   degc     = (int*)base;              base += N_NODES * 4;
    int*   fc       = (int*)base;              base += N_NODES * 4;   // adjacent to degc: one zero pass
    int*   off      = (int*)base;              base += (N_NODES + 1) * 4 + 4;
    float* dis      = (float*)base;            base += N_NODES * 4;
    int*   csr_src  = (int*)base;              base += N_EDGES * 4;
    float* csr_w    = (float*)base;            base += N_EDGES * 4;
    float* pool     = (float*)base;            base += NGRAPH * 256 * 4;
    float* comb     = (float*)base;            base += NGRAPH * 512 * 4;
    float* z1       = (float*)base;            base += NGRAPH * 256 * 4;
    float* cW1t     = (float*)base;            base += 512 * 256 * 4;
    float* cW2t     = (float*)base;            base += 256 * 64 * 4;
    unsigned short* xb   = (unsigned short*)base;  base += (size_t)N_NODES * 1280 * 2;  // aliased by agg4 later
    unsigned short* W1t  = (unsigned short*)base;  base += 512 * 1280 * 2;
    unsigned short* W2t  = (unsigned short*)base;  base += 512 * 512 * 2;
    unsigned short* W3t  = (unsigned short*)base;  base += 512 * 512 * 2;
    unsigned short* W4t  = (unsigned short*)base;  base += 256 * 512 * 2;
    unsigned short* h    = (unsigned short*)base;  base += (size_t)MPAD * 512 * 2;
    unsigned short* aggb = (unsigned short*)base;  base += (size_t)N_NODES * 512 * 2;
    float* agg4 = (float*)xb;  // alias: xb dead after GEMM1, agg4 written by gather4

    // ---- conversions (fused launches) ----
    conv_bf16<<<(N_NODES * 1280 / 4 + 255) / 256, 256, 0, stream>>>((const float4*)x, (u16x4*)xb, N_NODES * 1280 / 4);
    conv_transpose_w4<<<dim3(40, 16, 4), 256, 0, stream>>>(W1, W2, W3, W4, W1t, W2t, W3t, W4t);
    transpose_f32_2<<<dim3(16, 8, 2), 256, 0, stream>>>(cW1, cW2, cW1t, cW2t);

    // ---- CSR build ----
    zero_i32<<<(2 * N_NODES + 255) / 256, 256, 0, stream>>>(degc, 2 * N_NODES);  // degc + fc
    deg_count<<<(N_EDGES + 255) / 256, 256, 0, stream>>>(dstI, degc, N_EDGES);
    scan_offsets<<<1, 1024, 0, stream>>>(degc, off, dis, N_NODES);
    csr_fill<<<(N_EDGES + 255) / 256, 256, 0, stream>>>(srcI, dstI, off, fc, dis, csr_src, csr_w, N_EDGES);

    // ---- layer 1 ----
    gemm_bf16<<<dim3(512 / 128, MPAD / 64), 256, 0, stream>>>(xb, W1t, h, 1280, 512);
    gather_nodes<512, true, true><<<2500, 256, 0, stream>>>(h, off, csr_src, csr_w, dis, b1, aggb);
    // ---- layer 2 ----
    gemm_bf16<<<dim3(512 / 128, MPAD / 64), 256, 0, stream>>>(aggb, W2t, h, 512, 512);
    gather_nodes<512, true, true><<<2500, 256, 0, stream>>>(h, off, csr_src, csr_w, dis, b2, aggb);
    // ---- layer 3 ----
    gemm_bf16<<<dim3(512 / 128, MPAD / 64), 256, 0, stream>>>(aggb, W3t, h, 512, 512);
    gather_nodes<512, true, true><<<2500, 256, 0, stream>>>(h, off, csr_src, csr_w, dis, b3, aggb);
    // ---- layer 4 (no relu, fp32 out) ----
    gemm_bf16<<<dim3(256 / 128, MPAD / 64), 256, 0, stream>>>(aggb, W4t, h, 512, 256);
    gather_nodes<256, false, false><<<2500, 256, 0, stream>>>(h, off, csr_src, csr_w, dis, b4, agg4);

    // ---- pooling + head ----
    zero_f32<<<(NGRAPH * 256 + 255) / 256, 256, 0, stream>>>(pool, NGRAPH * 256);
    pool_partial<<<(N_NODES + PCHUNK - 1) / PCHUNK, 256, 0, stream>>>(agg4, bat, pool);
    head_comb<<<NGRAPH, 256, 0, stream>>>(pool, bat, vec, comb);
    head_z1<<<4096, 256, 0, stream>>>(comb, cW1t, cb1, z1);
    head_z2z3<<<NGRAPH, 256, 0, stream>>>(z1, cW2t, cb2, cW3, cb3, (float*)d_out);
}